// Round 5
// baseline (171.244 us; speedup 1.0000x reference)
//
#include <hip/hip_runtime.h>
#include <math.h>

#define NB 8
#define NC 256
#define NL 4096
#define NK 65
#define NSP 128   // supertiles per batch: 32 l-columns each (2 x 16 tiles)

typedef float vf4 __attribute__((ext_vector_type(4)));
typedef float vf2 __attribute__((ext_vector_type(2)));

// Per-block stat slots (sr, si, sq, pad) -- fully overwritten every launch.
__device__ float4 g_part[NB * NSP];

// XOR-swizzled LDS addressing: row-major [NC][8] float4, bank-group
// swizzle q ^ (row&7). Uniform 8-lanes-per-4-bank-group for every FFT
// stage access pattern and the store phase (b128 optimum).
__device__ __forceinline__ int lidx(int row, int q) {
    return (row << 3) + (q ^ (row & 7));
}

// ---------------------------------------------------------------------------
// Conv helpers (register sliding window, direct global loads; x rows are
// XCD-L2 resident via b = bid&7 swizzle, each float4 = one 64B line/lane).
// ---------------------------------------------------------------------------
#define LOAD16(W, L0, off)                                                  \
    {                                                                       \
        const int g0_ = (L0) + (off);                                       \
        if (g0_ >= 0 && g0_ + 16 <= NL) {  /* block-uniform branch */       \
            _Pragma("unroll")                                               \
            for (int q = 0; q < 4; ++q) {                                   \
                const float4 v_ = *(const float4*)(xr + g0_ + 4 * q);       \
                W[4*q+0] = v_.x; W[4*q+1] = v_.y;                           \
                W[4*q+2] = v_.z; W[4*q+3] = v_.w;                           \
            }                                                               \
        } else {                                                            \
            _Pragma("unroll")                                               \
            for (int q = 0; q < 16; ++q) {                                  \
                const int g_ = g0_ + q;                                     \
                W[q] = (g_ >= 0 && g_ < NL) ? xr[g_] : 0.0f;                \
            }                                                               \
        }                                                                   \
    }

#define CHUNK16(Lo, Hi, tb)                                                 \
    {                                                                       \
        _Pragma("unroll")                                                   \
        for (int j2 = 0; j2 < 16; ++j2) {                                   \
            const float kr_ = kre[(tb) + j2];   /* uniform -> s_load */     \
            const float ki_ = kim[(tb) + j2];                               \
            _Pragma("unroll")                                               \
            for (int i = 0; i < 16; ++i) {                                  \
                const int wi_ = i + j2;                                     \
                const float xv_ = (wi_ < 16) ? Lo[wi_] : Hi[wi_ - 16];      \
                sr[i] = fmaf(xv_, kr_, sr[i]);                              \
                si[i] = fmaf(xv_, ki_, si[i]);                              \
            }                                                               \
        }                                                                   \
    }

#define TAIL64(W)                                                           \
    {                                                                       \
        const float kr_ = kre[64];                                          \
        const float ki_ = kim[64];                                          \
        _Pragma("unroll")                                                   \
        for (int i = 0; i < 16; ++i) {                                      \
            sr[i] = fmaf(W[i], kr_, sr[i]);                                 \
            si[i] = fmaf(W[i], ki_, si[i]);                                 \
        }                                                                   \
    }

// stats (pre-weight) then weight multiply into own FFT row of lbuf4.
#define STATS_AND_WEIGHT()                                                  \
    {                                                                       \
        _Pragma("unroll")                                                   \
        for (int i = 0; i < 16; ++i) {                                      \
            tsr += sr[i];                                                   \
            tsi -= si[i];                                                   \
            tsq = fmaf(sr[i], sr[i], tsq);                                  \
            tsq = fmaf(si[i], si[i], tsq);                                  \
        }                                                                   \
        _Pragma("unroll")                                                   \
        for (int k = 0; k < 8; ++k) {                                       \
            float4 o;                                                       \
            o.x = sr[2*k]   * wgr + si[2*k]   * wgi;                        \
            o.y = sr[2*k]   * wgi - si[2*k]   * wgr;                        \
            o.z = sr[2*k+1] * wgr + si[2*k+1] * wgi;                        \
            o.w = sr[2*k+1] * wgi - si[2*k+1] * wgr;                        \
            lbuf4[lidx(t, k)] = o;                                          \
        }                                                                   \
    }

__device__ __forceinline__ int digitrev_shift(int pp) {
    int k = ((pp & 3) << 6) | (((pp >> 2) & 3) << 4)
          | (((pp >> 4) & 3) << 2) | ((pp >> 6) & 3);
    return k ^ 128;  // fftshift
}

// 4 radix-4 DIF stages over channels. Twiddles: every stage exponent e<64,
// so w1 comes from the per-thread tw64 register via __shfl; w2=w1^2, w3=w1*w2.
#define FFT256()                                                            \
    _Pragma("unroll")                                                       \
    for (int s = 0; s < 4; ++s) {                                           \
        const int shift = 2 * s;                                            \
        const int q = 64 >> shift;                                          \
        _Pragma("unroll")                                                   \
        for (int it = 0; it < 2; ++it) {                                    \
            int task = it * 256 + t;                                        \
            int lpp = task & 7;                                             \
            int m = task >> 3;                                              \
            int j = m & (q - 1);                                            \
            int blk = m >> (6 - shift);                                     \
            int base2 = blk << (8 - shift);                                 \
            int ca = base2 + j;                                             \
            float4 a0 = lbuf4[lidx(ca, lpp)];                               \
            float4 a1 = lbuf4[lidx(ca + q, lpp)];                           \
            float4 a2 = lbuf4[lidx(ca + 2*q, lpp)];                         \
            float4 a3 = lbuf4[lidx(ca + 3*q, lpp)];                         \
            float w1r, w1i;                                                 \
            if (s < 3) {                                                    \
                int e = j << shift;                                         \
                w1r = __shfl(tw64r, e);                                     \
                w1i = __shfl(tw64i, e);                                     \
            } else { w1r = 1.0f; w1i = 0.0f; }                              \
            float w2r = fmaf(w1r, w1r, -(w1i * w1i));                      \
            float w2i = 2.0f * w1r * w1i;                                   \
            float w3r = w2r * w1r - w2i * w1i;                              \
            float w3i = w2r * w1i + w2i * w1r;                              \
            float4 b0, b1, b2, b3;                                          \
            {                                                               \
                float t0r = a0.x + a2.x, t0i = a0.y + a2.y;                 \
                float t1r = a0.x - a2.x, t1i = a0.y - a2.y;                 \
                float t2r = a1.x + a3.x, t2i = a1.y + a3.y;                 \
                float t3r = a1.x - a3.x, t3i = a1.y - a3.y;                 \
                b0.x = t0r + t2r;       b0.y = t0i + t2i;                   \
                float b2r = t0r - t2r,  b2i = t0i - t2i;                    \
                float b1r = t1r + t3i,  b1i = t1i - t3r;                    \
                float b3r = t1r - t3i,  b3i = t1i + t3r;                    \
                b1.x = b1r*w1r - b1i*w1i;  b1.y = b1r*w1i + b1i*w1r;        \
                b2.x = b2r*w2r - b2i*w2i;  b2.y = b2r*w2i + b2i*w2r;        \
                b3.x = b3r*w3r - b3i*w3i;  b3.y = b3r*w3i + b3i*w3r;        \
            }                                                               \
            {                                                               \
                float t0r = a0.z + a2.z, t0i = a0.w + a2.w;                 \
                float t1r = a0.z - a2.z, t1i = a0.w - a2.w;                 \
                float t2r = a1.z + a3.z, t2i = a1.w + a3.w;                 \
                float t3r = a1.z - a3.z, t3i = a1.w - a3.w;                 \
                b0.z = t0r + t2r;       b0.w = t0i + t2i;                   \
                float b2r = t0r - t2r,  b2i = t0i - t2i;                    \
                float b1r = t1r + t3i,  b1i = t1i - t3r;                    \
                float b3r = t1r - t3i,  b3i = t1i + t3r;                    \
                b1.z = b1r*w1r - b1i*w1i;  b1.w = b1r*w1i + b1i*w1r;        \
                b2.z = b2r*w2r - b2i*w2i;  b2.w = b2r*w2i + b2i*w2r;        \
                b3.z = b3r*w3r - b3i*w3i;  b3.w = b3r*w3i + b3i*w3r;        \
            }                                                               \
            lbuf4[lidx(ca, lpp)]         = b0;                              \
            lbuf4[lidx(ca + q, lpp)]     = b1;                              \
            lbuf4[lidx(ca + 2*q, lpp)]   = b2;                              \
            lbuf4[lidx(ca + 3*q, lpp)]   = b3;                              \
        }                                                                   \
        __syncthreads();                                                    \
    }

// digit-reverse + fftshift + NONTEMPORAL un-normalized store for tile at L0.
#define STORE_TILE(L0)                                                      \
    _Pragma("unroll")                                                       \
    for (int it = 0; it < 8; ++it) {                                        \
        int task = it * 256 + t;                                            \
        int lpp = task & 7;                                                 \
        int pp = task >> 3;                                                 \
        float4 v = lbuf4[lidx(pp, lpp)];                                    \
        int cout = digitrev_shift(pp);                                      \
        if (interleaved) {                                                  \
            size_t fi = 2 * ((size_t)(b * NC + cout) * NL + (L0)) + 4 * lpp;\
            if (fi + 4 <= (size_t)out_size) {                               \
                vf4 o4; o4.x = v.x; o4.y = v.y; o4.z = v.z; o4.w = v.w;     \
                __builtin_nontemporal_store(o4, (vf4*)(out + fi));          \
            }                                                               \
        } else {                                                            \
            size_t fi = (size_t)(b * NC + cout) * NL + (L0) + 2 * lpp;      \
            if (fi + 2 <= (size_t)out_size) {                               \
                vf2 o2; o2.x = v.x; o2.y = v.z;                             \
                __builtin_nontemporal_store(o2, (vf2*)(out + fi));          \
            }                                                               \
        }                                                                   \
    }

// ---------------------------------------------------------------------------
// Fused, two tiles per block, software-pipelined: tile B's window loads are
// issued BEFORE tile A's FFT barriers (global loads stay in flight across
// s_barrier; FFT uses only lgkm), so conv B never stalls on memory. Grid =
// 1024 blocks = exactly 4/CU in ONE residency shift. LDS padded to 36 KB +
// launch_bounds(256,4): the proven low-traffic regime (R3: 5/CU overflows
// XCD L2 -> HBM RMW amplification). out stores bypass L2 (nt) so the whole
// 4 MB XCD L2 serves the x sliding window (R4: confirmed, FETCH 49->16.6 MB).
// ---------------------------------------------------------------------------
__global__ __launch_bounds__(256, 4) void fused_conv_fft_kernel(
    const float* __restrict__ x,
    const float* __restrict__ kre,
    const float* __restrict__ kim,
    const float* __restrict__ wmag,
    const float* __restrict__ wang,
    float* __restrict__ out,
    int out_size)
{
    // 36 KB allocated (indexing stays < NC*8): forces <=4 blocks/CU.
    __shared__ __align__(16) float4 lbuf4[NC * 9];

    const int t = threadIdx.x;              // channel
    const int b = blockIdx.x & 7;           // batch == XCD
    const int sp = blockIdx.x >> 3;         // supertile (0..127)
    const int l0A = sp << 5;
    const int l0B = l0A + 16;
    const int lane = t & 63, wv = t >> 6;

    const float* xr = x + (size_t)b * NC * NL + (size_t)t * NL;  // own row
    const bool interleaved = (out_size >= 2 * NB * NC * NL);

    float tsr = 0.0f, tsi = 0.0f, tsq = 0.0f;
    float sr[16], si[16];

    // ================= tile A: conv (4-buffer window) =================
    #pragma unroll
    for (int i = 0; i < 16; ++i) { sr[i] = 0.0f; si[i] = 0.0f; }
    float W0[16], W1[16], W2[16], W3[16];
    LOAD16(W0, l0A, -32);
    LOAD16(W1, l0A, -16);
    LOAD16(W2, l0A, 0);
    LOAD16(W3, l0A, 16);
    CHUNK16(W0, W1, 0);      // taps  0..15
    LOAD16(W0, l0A, 32);     // words [32,48) -> chunk 48 + tail
    CHUNK16(W1, W2, 16);     // taps 16..31
    CHUNK16(W2, W3, 32);     // taps 32..47
    CHUNK16(W3, W0, 48);     // taps 48..63
    TAIL64(W0);              // tap 64

    // ---- per-block constants (once, serve both tiles) ----
    float sw, cw;
    sincosf(wang[t], &sw, &cw);
    const float wm = wmag[t];
    const float wgr =  wm * cw;             // weight WITHOUT inv_std
    const float wgi = -wm * sw;
    float tw64r, tw64i;                     // exp(-2*pi*i*lane/256)
    {
        float ang = (float)lane * 0.024543692606170260f;  // 2*pi/256
        float s, c;
        sincosf(ang, &s, &c);
        tw64r = c; tw64i = -s;
    }

    STATS_AND_WEIGHT();      // tile A -> lbuf4

    // ---- issue tile B's leading window loads; they ride out FFT A's
    //      barriers in the vmcnt queue (consumers are ~3000 cyc away) ----
    float B0[16], B1[16];
    LOAD16(B0, l0B, -32);
    LOAD16(B1, l0B, -16);

    __syncthreads();
    FFT256();                // tile A (4 barriers inside)

    // ---- issue B's remaining loads BEFORE the nt stores (loads first in
    //      the vmcnt queue -> conv B never waits on store completion) ----
    float B2[16], B3[16];
    LOAD16(B2, l0B, 0);
    LOAD16(B3, l0B, 16);

    STORE_TILE(l0A);

    // ================= tile B: conv (reuses W0 as 5th buffer) ========
    #pragma unroll
    for (int i = 0; i < 16; ++i) { sr[i] = 0.0f; si[i] = 0.0f; }
    LOAD16(W0, l0B, 32);     // last window chunk, ~2000 cyc of slack
    CHUNK16(B0, B1, 0);      // taps  0..15
    CHUNK16(B1, B2, 16);     // taps 16..31
    CHUNK16(B2, B3, 32);     // taps 32..47
    CHUNK16(B3, W0, 48);     // taps 48..63
    TAIL64(W0);              // tap 64

    __syncthreads();         // all store-A LDS reads complete

    STATS_AND_WEIGHT();      // tile B -> lbuf4

    __syncthreads();
    FFT256();                // tile B

    STORE_TILE(l0B);

    // ---- block stats (A+B) -> dedicated slot (reduce via LDS alias) ----
    #pragma unroll
    for (int off = 32; off > 0; off >>= 1) {
        tsr += __shfl_down(tsr, off);
        tsi += __shfl_down(tsi, off);
        tsq += __shfl_down(tsq, off);
    }
    __syncthreads();                        // store-phase reads done
    float* redf = (float*)lbuf4;
    if (lane == 0) { redf[wv*3+0] = tsr; redf[wv*3+1] = tsi; redf[wv*3+2] = tsq; }
    __syncthreads();
    if (t == 0) {
        float a0 = 0.0f, a1 = 0.0f, a2 = 0.0f;
        #pragma unroll
        for (int i = 0; i < 4; ++i) { a0 += redf[i*3]; a1 += redf[i*3+1]; a2 += redf[i*3+2]; }
        g_part[b * NSP + sp] = make_float4(a0, a1, a2, 0.0f);
    }
}

// ---------------------------------------------------------------------------
// Per-batch inv_std from g_part (each block redundantly reduces its own
// batch's 128 slots -- 2 KB, L2-hot) + contiguous nontemporal scale of its
// out range. XCD-affine: block j -> batch j&7 (same swizzle as fused).
// ---------------------------------------------------------------------------
__global__ __launch_bounds__(256) void scale_out_kernel(
    float* __restrict__ out, int out_size)
{
    __shared__ float sred[13];
    const int t = threadIdx.x;
    const int j = blockIdx.x;               // 0..2047
    const int b = j & 7;                    // batch == XCD
    const int seg = j >> 3;                 // 256 segments per batch
    const int lane = t & 63, wv = t >> 6;

    // reduce batch b's 128 slots (threads 128..255 contribute zero)
    float psr = 0.0f, psi = 0.0f, psq = 0.0f;
    if (t < NSP) {
        float4 p = g_part[b * NSP + t];
        psr = p.x; psi = p.y; psq = p.z;
    }
    #pragma unroll
    for (int off = 32; off > 0; off >>= 1) {
        psr += __shfl_down(psr, off);
        psi += __shfl_down(psi, off);
        psq += __shfl_down(psq, off);
    }
    if (lane == 0) { sred[wv*3+0] = psr; sred[wv*3+1] = psi; sred[wv*3+2] = psq; }
    __syncthreads();
    if (t == 0) {
        float a0 = 0.0f, a1 = 0.0f, a2 = 0.0f;
        #pragma unroll
        for (int i = 0; i < 4; ++i) { a0 += sred[i*3]; a1 += sred[i*3+1]; a2 += sred[i*3+2]; }
        const float n = (float)(NC * NL);
        float var = (a2 - (a0*a0 + a1*a1)/n) / (n - 1.0f);
        sred[12] = rsqrtf(var);
    }
    __syncthreads();
    const float inv = sred[12];

    const int fpbatch = out_size >> 3;      // floats per batch
    const int fpseg = fpbatch >> 8;         // floats per segment
    const int base = b * fpbatch + seg * fpseg;
    if ((fpseg & 3) == 0 && ((size_t)(out + base) & 15) == 0) {
        const int n4 = fpseg >> 2;
        for (int i = t; i < n4; i += 256) {
            vf4* p4 = (vf4*)(out + base) + i;
            vf4 v = __builtin_nontemporal_load(p4);
            v.x *= inv; v.y *= inv; v.z *= inv; v.w *= inv;
            __builtin_nontemporal_store(v, p4);
        }
    } else {
        for (int i = t; i < fpseg; i += 256) out[base + i] *= inv;
    }
    // tail (out_size not divisible by 2048): belongs to the last batch,
    // and block j==2047 has b==7.
    if (j == 2047) {
        for (int i = ((out_size >> 11) << 11) + t; i < out_size; i += 256)
            out[i] *= inv;
    }
}

extern "C" void kernel_launch(void* const* d_in, const int* in_sizes, int n_in,
                              void* d_out, int out_size, void* d_ws, size_t ws_size,
                              hipStream_t stream)
{
    const float* x   = (const float*)d_in[0];
    const float* kre = (const float*)d_in[1];
    const float* kim = (const float*)d_in[2];
    const float* wm  = (const float*)d_in[3];
    const float* wa  = (const float*)d_in[4];
    float* out = (float*)d_out;
    (void)d_ws; (void)ws_size;

    fused_conv_fft_kernel<<<NB * NSP, 256, 0, stream>>>(x, kre, kim, wm, wa,
                                                        out, out_size);
    scale_out_kernel<<<2048, 256, 0, stream>>>(out, out_size);
}

// Round 6
// 154.164 us; speedup vs baseline: 1.1108x; 1.1108x over previous
//
#include <hip/hip_runtime.h>
#include <math.h>

#define NB 8
#define NC 256
#define NL 4096
#define NK 65
#define NSL (NL / 16)   // 256 l-tiles per batch

typedef float vf4 __attribute__((ext_vector_type(4)));
typedef float vf2 __attribute__((ext_vector_type(2)));

// Per-block stat slots (sr, si, sq, pad) -- fully overwritten every launch,
// so no zeroing pass and no atomics are needed.
__device__ float4 g_part[NB * NSL];

// XOR-swizzled LDS addressing: row-major [NC][8] float4, bank-group
// swizzle q ^ (row&7). Uniform 8-lanes-per-4-bank-group for every FFT
// stage access pattern and the store phase (b128 optimum), no pad needed.
__device__ __forceinline__ int lidx(int row, int q) {
    return (row << 3) + (q ^ (row & 7));
}

// ---------------------------------------------------------------------------
// Conv helpers (register sliding window, direct global loads; x rows are
// XCD-L2 resident via b = bid&7 swizzle, each float4 = one 64B line/lane).
// ---------------------------------------------------------------------------
#define LOAD16(W, off)                                                      \
    {                                                                       \
        const int g0_ = l0 + (off);                                         \
        if (g0_ >= 0 && g0_ + 16 <= NL) {  /* block-uniform branch */       \
            _Pragma("unroll")                                               \
            for (int q = 0; q < 4; ++q) {                                   \
                const float4 v_ = *(const float4*)(xr + g0_ + 4 * q);       \
                W[4*q+0] = v_.x; W[4*q+1] = v_.y;                           \
                W[4*q+2] = v_.z; W[4*q+3] = v_.w;                           \
            }                                                               \
        } else {                                                            \
            _Pragma("unroll")                                               \
            for (int q = 0; q < 16; ++q) {                                  \
                const int g_ = g0_ + q;                                     \
                W[q] = (g_ >= 0 && g_ < NL) ? xr[g_] : 0.0f;                \
            }                                                               \
        }                                                                   \
    }

#define CHUNK16(Lo, Hi, tb)                                                 \
    {                                                                       \
        _Pragma("unroll")                                                   \
        for (int j2 = 0; j2 < 16; ++j2) {                                   \
            const float kr_ = kre[(tb) + j2];   /* uniform -> s_load */     \
            const float ki_ = kim[(tb) + j2];                               \
            _Pragma("unroll")                                               \
            for (int i = 0; i < 16; ++i) {                                  \
                const int wi_ = i + j2;                                     \
                const float xv_ = (wi_ < 16) ? Lo[wi_] : Hi[wi_ - 16];      \
                sr[i] = fmaf(xv_, kr_, sr[i]);                              \
                si[i] = fmaf(xv_, ki_, si[i]);                              \
            }                                                               \
        }                                                                   \
    }

__device__ __forceinline__ int digitrev_shift(int pp) {
    int k = ((pp & 3) << 6) | (((pp >> 2) & 3) << 4)
          | (((pp >> 4) & 3) << 2) | ((pp >> 6) & 3);
    return k ^ 128;  // fftshift
}

// ---------------------------------------------------------------------------
// Fused: conv (65 taps, 4-buffer deep-prefetch register window) + pre-weight
// stats + weight (inv_std deferred by linearity) + 256-pt radix-4 FFT over
// channels + fftshift + NONTEMPORAL un-normalized store + per-block stat slot.
// R6: LDS exactly 32 KB -> 5 blocks/CU. R3 showed 5/CU thrashes the XCD L2
// when stores go THROUGH L2; R4's nt stores removed out from L2 entirely, so
// x (4 MB = one batch per XCD) is now the only L2 tenant and the extra
// resident block is pure latency-hiding upside. R5 lesson: no cross-phase
// register holding (spills at the compiler's 64-VGPR choice; WRITE_SIZE is
// the spill tripwire).
// ---------------------------------------------------------------------------
__global__ __launch_bounds__(256, 5) void fused_conv_fft_kernel(
    const float* __restrict__ x,
    const float* __restrict__ kre,
    const float* __restrict__ kim,
    const float* __restrict__ wmag,
    const float* __restrict__ wang,
    float* __restrict__ out,
    int out_size)
{
    __shared__ __align__(16) float4 lbuf4[NC * 8];  // exactly 32768 B

    const int t = threadIdx.x;              // channel
    const int b = blockIdx.x & 7;           // batch == XCD
    const int st = blockIdx.x >> 3;         // tile index within batch
    const int l0 = st << 4;                 // tile base
    const int lane = t & 63, wv = t >> 6;

    const float* xr = x + (size_t)b * NC * NL + (size_t)t * NL;  // own row
    const bool interleaved = (out_size >= 2 * NB * NC * NL);

    float sr[16], si[16];
    #pragma unroll
    for (int i = 0; i < 16; ++i) { sr[i] = 0.0f; si[i] = 0.0f; }

    // ---- conv: 65 taps, 4-buffer prefetched sliding window, no barriers --
    // 16 dwordx4 loads issued before the first FMA; the W0 reload has two
    // full chunks (1024 FMAs) of slack before its consumer.
    float W0[16], W1[16], W2[16], W3[16];
    LOAD16(W0, -32);
    LOAD16(W1, -16);
    LOAD16(W2, 0);
    LOAD16(W3, 16);
    CHUNK16(W0, W1, 0);      // taps  0..15
    LOAD16(W0, 32);          // words [32,48) -> consumed by chunk 48 + tail
    CHUNK16(W1, W2, 16);     // taps 16..31
    CHUNK16(W2, W3, 32);     // taps 32..47
    CHUNK16(W3, W0, 48);     // taps 48..63
    {   // tail tap j = 64: words rel [32, 47] == W0
        const float kr_ = kre[64];
        const float ki_ = kim[64];
        #pragma unroll
        for (int i = 0; i < 16; ++i) {
            sr[i] = fmaf(W0[i], kr_, sr[i]);
            si[i] = fmaf(W0[i], ki_, si[i]);
        }
    }

    // ---- stats on y = (sr, -si), PRE-weight (un-normalized) ----
    float tsr = 0.0f, tsi = 0.0f, tsq = 0.0f;
    #pragma unroll
    for (int i = 0; i < 16; ++i) {
        tsr += sr[i];
        tsi -= si[i];
        tsq = fmaf(sr[i], sr[i], tsq);
        tsq = fmaf(si[i], si[i], tsq);
    }

    // ---- weight & twiddle constants (computed HERE to keep conv-phase
    //      register liveness low) ----
    float sw, cw;
    sincosf(wang[t], &sw, &cw);
    const float wm = wmag[t];
    const float wgr =  wm * cw;             // weight WITHOUT inv_std
    const float wgi = -wm * sw;
    float tw64r, tw64i;                     // exp(-2*pi*i*lane/256)
    {
        float ang = (float)lane * 0.024543692606170260f;  // 2*pi/256
        float s, c;
        sincosf(ang, &s, &c);
        tw64r = c; tw64i = -s;
    }

    // ---- weight: y' = y * (wgr + i*wgi) -> own FFT row (first LDS use) ----
    #pragma unroll
    for (int k = 0; k < 8; ++k) {
        float4 o;
        o.x = sr[2*k]   * wgr + si[2*k]   * wgi;
        o.y = sr[2*k]   * wgi - si[2*k]   * wgr;
        o.z = sr[2*k+1] * wgr + si[2*k+1] * wgi;
        o.w = sr[2*k+1] * wgi - si[2*k+1] * wgr;
        lbuf4[lidx(t, k)] = o;
    }
    __syncthreads();

    // ---- 4 radix-4 DIF stages over channels ----
    // Twiddles: all stage exponents satisfy e<64, so w1 comes from the
    // per-thread tw64 register via __shfl; w2 = w1^2, w3 = w1*w2.
    #pragma unroll
    for (int s = 0; s < 4; ++s) {
        const int shift = 2 * s;
        const int q = 64 >> shift;
        #pragma unroll
        for (int it = 0; it < 2; ++it) {
            int task = it * 256 + t;       // 512 tasks = 64 butterflies x 8 lpairs
            int lpp = task & 7;
            int m = task >> 3;
            int j = m & (q - 1);
            int blk = m >> (6 - shift);
            int base2 = blk << (8 - shift);

            int ca = base2 + j;
            float4 a0 = lbuf4[lidx(ca, lpp)];
            float4 a1 = lbuf4[lidx(ca + q, lpp)];
            float4 a2 = lbuf4[lidx(ca + 2*q, lpp)];
            float4 a3 = lbuf4[lidx(ca + 3*q, lpp)];

            float w1r, w1i;
            if (s < 3) {
                int e = j << shift;        // e < 64 for all stages
                w1r = __shfl(tw64r, e);
                w1i = __shfl(tw64i, e);
            } else {
                w1r = 1.0f; w1i = 0.0f;    // stage 3: e == 0
            }
            float w2r = fmaf(w1r, w1r, -(w1i * w1i));
            float w2i = 2.0f * w1r * w1i;
            float w3r = w2r * w1r - w2i * w1i;
            float w3i = w2r * w1i + w2i * w1r;

            float4 b0, b1, b2, b3;
            {
                float t0r = a0.x + a2.x, t0i = a0.y + a2.y;
                float t1r = a0.x - a2.x, t1i = a0.y - a2.y;
                float t2r = a1.x + a3.x, t2i = a1.y + a3.y;
                float t3r = a1.x - a3.x, t3i = a1.y - a3.y;
                b0.x = t0r + t2r;       b0.y = t0i + t2i;
                float b2r = t0r - t2r,  b2i = t0i - t2i;
                float b1r = t1r + t3i,  b1i = t1i - t3r;
                float b3r = t1r - t3i,  b3i = t1i + t3r;
                b1.x = b1r*w1r - b1i*w1i;  b1.y = b1r*w1i + b1i*w1r;
                b2.x = b2r*w2r - b2i*w2i;  b2.y = b2r*w2i + b2i*w2r;
                b3.x = b3r*w3r - b3i*w3i;  b3.y = b3r*w3i + b3i*w3r;
            }
            {
                float t0r = a0.z + a2.z, t0i = a0.w + a2.w;
                float t1r = a0.z - a2.z, t1i = a0.w - a2.w;
                float t2r = a1.z + a3.z, t2i = a1.w + a3.w;
                float t3r = a1.z - a3.z, t3i = a1.w - a3.w;
                b0.z = t0r + t2r;       b0.w = t0i + t2i;
                float b2r = t0r - t2r,  b2i = t0i - t2i;
                float b1r = t1r + t3i,  b1i = t1i - t3r;
                float b3r = t1r - t3i,  b3i = t1i + t3r;
                b1.z = b1r*w1r - b1i*w1i;  b1.w = b1r*w1i + b1i*w1r;
                b2.z = b2r*w2r - b2i*w2i;  b2.w = b2r*w2i + b2i*w2r;
                b3.z = b3r*w3r - b3i*w3i;  b3.w = b3r*w3i + b3i*w3r;
            }
            lbuf4[lidx(ca, lpp)]         = b0;
            lbuf4[lidx(ca + q, lpp)]     = b1;
            lbuf4[lidx(ca + 2*q, lpp)]   = b2;
            lbuf4[lidx(ca + 3*q, lpp)]   = b3;
        }
        __syncthreads();
    }

    // ---- store (un-normalized): digit-reverse + fftshift, NONTEMPORAL ----
    #pragma unroll
    for (int it = 0; it < 8; ++it) {
        int task = it * 256 + t;
        int lpp = task & 7;
        int pp = task >> 3;
        float4 v = lbuf4[lidx(pp, lpp)];
        int cout = digitrev_shift(pp);
        if (interleaved) {
            size_t fi = 2 * ((size_t)(b * NC + cout) * NL + l0) + 4 * lpp;
            if (fi + 4 <= (size_t)out_size) {
                vf4 o4; o4.x = v.x; o4.y = v.y; o4.z = v.z; o4.w = v.w;
                __builtin_nontemporal_store(o4, (vf4*)(out + fi));
            }
        } else {
            size_t fi = (size_t)(b * NC + cout) * NL + l0 + 2 * lpp;
            if (fi + 2 <= (size_t)out_size) {
                vf2 o2; o2.x = v.x; o2.y = v.z;
                __builtin_nontemporal_store(o2, (vf2*)(out + fi));
            }
        }
    }

    // ---- block stats -> dedicated slot (reduce via LDS alias) ----
    #pragma unroll
    for (int off = 32; off > 0; off >>= 1) {
        tsr += __shfl_down(tsr, off);
        tsi += __shfl_down(tsi, off);
        tsq += __shfl_down(tsq, off);
    }
    __syncthreads();                        // store-phase reads done
    float* redf = (float*)lbuf4;
    if (lane == 0) { redf[wv*3+0] = tsr; redf[wv*3+1] = tsi; redf[wv*3+2] = tsq; }
    __syncthreads();
    if (t == 0) {
        float a0 = 0.0f, a1 = 0.0f, a2 = 0.0f;
        #pragma unroll
        for (int i = 0; i < 4; ++i) { a0 += redf[i*3]; a1 += redf[i*3+1]; a2 += redf[i*3+2]; }
        g_part[b * NSL + st] = make_float4(a0, a1, a2, 0.0f);
    }
}

// ---------------------------------------------------------------------------
// Per-batch inv_std from g_part (each block redundantly reduces its own
// batch's 256 slots -- 4 KB, L2-hot) + contiguous nontemporal scale of its
// out range. XCD-affine: block j -> batch j&7 (same swizzle as fused).
// ---------------------------------------------------------------------------
__global__ __launch_bounds__(256) void scale_out_kernel(
    float* __restrict__ out, int out_size)
{
    __shared__ float sred[13];
    const int t = threadIdx.x;
    const int j = blockIdx.x;               // 0..2047
    const int b = j & 7;                    // batch == XCD
    const int seg = j >> 3;                 // 256 segments per batch
    const int lane = t & 63, wv = t >> 6;

    // reduce batch b's 256 slots (thread t -> slot t)
    float4 p = g_part[b * NSL + t];
    float psr = p.x, psi = p.y, psq = p.z;
    #pragma unroll
    for (int off = 32; off > 0; off >>= 1) {
        psr += __shfl_down(psr, off);
        psi += __shfl_down(psi, off);
        psq += __shfl_down(psq, off);
    }
    if (lane == 0) { sred[wv*3+0] = psr; sred[wv*3+1] = psi; sred[wv*3+2] = psq; }
    __syncthreads();
    if (t == 0) {
        float a0 = 0.0f, a1 = 0.0f, a2 = 0.0f;
        #pragma unroll
        for (int i = 0; i < 4; ++i) { a0 += sred[i*3]; a1 += sred[i*3+1]; a2 += sred[i*3+2]; }
        const float n = (float)(NC * NL);
        float var = (a2 - (a0*a0 + a1*a1)/n) / (n - 1.0f);
        sred[12] = rsqrtf(var);
    }
    __syncthreads();
    const float inv = sred[12];

    const int fpbatch = out_size >> 3;      // floats per batch
    const int fpseg = fpbatch >> 8;         // floats per segment
    const int base = b * fpbatch + seg * fpseg;
    if ((fpseg & 3) == 0 && ((size_t)(out + base) & 15) == 0) {
        const int n4 = fpseg >> 2;
        for (int i = t; i < n4; i += 256) {
            vf4* p4 = (vf4*)(out + base) + i;
            vf4 v = __builtin_nontemporal_load(p4);
            v.x *= inv; v.y *= inv; v.z *= inv; v.w *= inv;
            __builtin_nontemporal_store(v, p4);
        }
    } else {
        for (int i = t; i < fpseg; i += 256) out[base + i] *= inv;
    }
    // tail (out_size not divisible by 2048): belongs to the last batch,
    // and block j==2047 has b==7.
    if (j == 2047) {
        for (int i = ((out_size >> 11) << 11) + t; i < out_size; i += 256)
            out[i] *= inv;
    }
}

extern "C" void kernel_launch(void* const* d_in, const int* in_sizes, int n_in,
                              void* d_out, int out_size, void* d_ws, size_t ws_size,
                              hipStream_t stream)
{
    const float* x   = (const float*)d_in[0];
    const float* kre = (const float*)d_in[1];
    const float* kim = (const float*)d_in[2];
    const float* wm  = (const float*)d_in[3];
    const float* wa  = (const float*)d_in[4];
    float* out = (float*)d_out;
    (void)d_ws; (void)ws_size;

    fused_conv_fft_kernel<<<NB * NSL, 256, 0, stream>>>(x, kre, kim, wm, wa,
                                                        out, out_size);
    scale_out_kernel<<<2048, 256, 0, stream>>>(out, out_size);
}

// Round 7
// 137.055 us; speedup vs baseline: 1.2495x; 1.1248x over previous
//
#include <hip/hip_runtime.h>
#include <math.h>

#define NB 8
#define NC 256
#define NL 4096
#define NK 65
#define NSL (NL / 16)   // 256 l-tiles per batch

typedef float vf4 __attribute__((ext_vector_type(4)));
typedef float vf2 __attribute__((ext_vector_type(2)));

// Per-block stat slots (sr, si, sq, pad) -- fully overwritten every launch,
// so no zeroing pass and no atomics are needed.
__device__ float4 g_part[NB * NSL];

// XOR-swizzled LDS addressing: row-major [NC][8] float4, bank-group
// swizzle q ^ (row&7). Uniform 8-lanes-per-4-bank-group for every FFT
// stage access pattern (b128 optimum), no pad needed.
__device__ __forceinline__ int lidx(int row, int q) {
    return (row << 3) + (q ^ (row & 7));
}

// ---------------------------------------------------------------------------
// Conv helpers (register sliding window, direct global loads; x rows are
// XCD-L2 resident via b = bid&7 swizzle, each float4 = one 64B line/lane).
// Accumulators are PACKED (re,im) vf2 -> v_pk_fma_f32: one instruction per
// tap per output instead of two.
// ---------------------------------------------------------------------------
#define LOAD16(W, off)                                                      \
    {                                                                       \
        const int g0_ = l0 + (off);                                         \
        if (g0_ >= 0 && g0_ + 16 <= NL) {  /* block-uniform branch */       \
            _Pragma("unroll")                                               \
            for (int q = 0; q < 4; ++q) {                                   \
                const float4 v_ = *(const float4*)(xr + g0_ + 4 * q);       \
                W[4*q+0] = v_.x; W[4*q+1] = v_.y;                           \
                W[4*q+2] = v_.z; W[4*q+3] = v_.w;                           \
            }                                                               \
        } else {                                                            \
            _Pragma("unroll")                                               \
            for (int q = 0; q < 16; ++q) {                                  \
                const int g_ = g0_ + q;                                     \
                W[q] = (g_ >= 0 && g_ < NL) ? xr[g_] : 0.0f;                \
            }                                                               \
        }                                                                   \
    }

#define CHUNK16(Lo, Hi, tb)                                                 \
    {                                                                       \
        _Pragma("unroll")                                                   \
        for (int j2 = 0; j2 < 16; ++j2) {                                   \
            vf2 k2_; k2_.x = kre[(tb) + j2]; k2_.y = kim[(tb) + j2];        \
            _Pragma("unroll")                                               \
            for (int i = 0; i < 16; ++i) {                                  \
                const int wi_ = i + j2;                                     \
                const float xv_ = (wi_ < 16) ? Lo[wi_] : Hi[wi_ - 16];      \
                vf2 xv2_; xv2_.x = xv_; xv2_.y = xv_;                       \
                s2[i] = __builtin_elementwise_fma(xv2_, k2_, s2[i]);        \
            }                                                               \
        }                                                                   \
    }

__device__ __forceinline__ int digitrev_shift(int pp) {
    int k = ((pp & 3) << 6) | (((pp >> 2) & 3) << 4)
          | (((pp >> 4) & 3) << 2) | ((pp >> 6) & 3);
    return k ^ 128;  // fftshift
}

// ---------------------------------------------------------------------------
// Fused: conv (65 taps, 4-buffer prefetch register window, packed-f32 FMA)
// + pre-weight stats + weight (inv_std deferred by linearity) + 256-pt
// radix-4 FFT over channels (stages 0-2 in LDS; stage 3 fused into the
// digit-reversed NONTEMPORAL store -- its butterflies with q=1, w=1 emit
// final values for 4 consecutive rows straight from registers) + per-block
// stat slot. LDS padded to 36 KB + launch_bounds(256,4): proven regime
// (R3/R6: 5/CU caps VGPR at 48 -> scratch spill, WRITE_SIZE is the
// tripwire; R4: nt stores keep out of L2 so x owns the XCD L2).
// ---------------------------------------------------------------------------
__global__ __launch_bounds__(256, 4) void fused_conv_fft_kernel(
    const float* __restrict__ x,
    const float* __restrict__ kre,
    const float* __restrict__ kim,
    const float* __restrict__ wmag,
    const float* __restrict__ wang,
    float* __restrict__ out,
    int out_size)
{
    // 36 KB allocated (indexing stays < NC*8): forces <=4 blocks/CU.
    __shared__ __align__(16) float4 lbuf4[NC * 9];

    const int t = threadIdx.x;              // channel
    const int b = blockIdx.x & 7;           // batch == XCD
    const int st = blockIdx.x >> 3;         // tile index within batch
    const int l0 = st << 4;                 // tile base
    const int lane = t & 63, wv = t >> 6;

    const float* xr = x + (size_t)b * NC * NL + (size_t)t * NL;  // own row
    const bool interleaved = (out_size >= 2 * NB * NC * NL);

    vf2 s2[16];                             // packed (sr, si) accumulators
    #pragma unroll
    for (int i = 0; i < 16; ++i) { s2[i].x = 0.0f; s2[i].y = 0.0f; }

    // ---- conv: 65 taps, 4-buffer prefetched sliding window, no barriers --
    float W0[16], W1[16], W2[16], W3[16];
    LOAD16(W0, -32);
    LOAD16(W1, -16);
    LOAD16(W2, 0);
    LOAD16(W3, 16);
    CHUNK16(W0, W1, 0);      // taps  0..15
    LOAD16(W0, 32);          // words [32,48) -> consumed by chunk 48 + tail
    CHUNK16(W1, W2, 16);     // taps 16..31
    CHUNK16(W2, W3, 32);     // taps 32..47
    CHUNK16(W3, W0, 48);     // taps 48..63
    {   // tail tap j = 64: words rel [32, 47] == W0
        vf2 k2_; k2_.x = kre[64]; k2_.y = kim[64];
        #pragma unroll
        for (int i = 0; i < 16; ++i) {
            vf2 xv2_; xv2_.x = W0[i]; xv2_.y = W0[i];
            s2[i] = __builtin_elementwise_fma(xv2_, k2_, s2[i]);
        }
    }

    // ---- stats on y = (sr, -si), PRE-weight (un-normalized), packed ----
    vf2 tsum; tsum.x = 0.0f; tsum.y = 0.0f;
    vf2 tsq2; tsq2.x = 0.0f; tsq2.y = 0.0f;
    #pragma unroll
    for (int i = 0; i < 16; ++i) {
        tsum = tsum + s2[i];
        tsq2 = __builtin_elementwise_fma(s2[i], s2[i], tsq2);
    }
    float tsr = tsum.x, tsi = -tsum.y, tsq = tsq2.x + tsq2.y;

    // ---- weight & twiddle constants (after conv: low conv-phase liveness) --
    float sw, cw;
    sincosf(wang[t], &sw, &cw);
    const float wm = wmag[t];
    const float wgr =  wm * cw;             // weight WITHOUT inv_std
    const float wgi = -wm * sw;
    vf2 wgA; wgA.x = wgr; wgA.y = wgi;      // multiplies sr
    vf2 wgB; wgB.x = wgi; wgB.y = -wgr;     // multiplies si
    float tw64r, tw64i;                     // exp(-2*pi*i*lane/256)
    {
        float ang = (float)lane * 0.024543692606170260f;  // 2*pi/256
        float s, c;
        sincosf(ang, &s, &c);
        tw64r = c; tw64i = -s;
    }

    // ---- weight: y' = y * (wgr + i*wgi) -> own FFT row (first LDS use) ----
    #pragma unroll
    for (int k = 0; k < 8; ++k) {
        vf2 srA; srA.x = s2[2*k].x;   srA.y = s2[2*k].x;
        vf2 siA; siA.x = s2[2*k].y;   siA.y = s2[2*k].y;
        vf2 o0 = __builtin_elementwise_fma(srA, wgA, siA * wgB);
        vf2 srB; srB.x = s2[2*k+1].x; srB.y = s2[2*k+1].x;
        vf2 siB; siB.x = s2[2*k+1].y; siB.y = s2[2*k+1].y;
        vf2 o1 = __builtin_elementwise_fma(srB, wgA, siB * wgB);
        float4 o;
        o.x = o0.x; o.y = o0.y; o.z = o1.x; o.w = o1.y;
        lbuf4[lidx(t, k)] = o;
    }
    __syncthreads();

    // ---- FFT stages 0..2 over channels (LDS) ----
    // Twiddles: stage exponents e<64 -> w1 from per-thread tw64 via __shfl;
    // w2 = w1^2, w3 = w1*w2 (double-angle, exact).
    #pragma unroll
    for (int s = 0; s < 3; ++s) {
        const int shift = 2 * s;
        const int q = 64 >> shift;
        #pragma unroll
        for (int it = 0; it < 2; ++it) {
            int task = it * 256 + t;       // 512 tasks = 64 butterflies x 8 lpairs
            int lpp = task & 7;
            int m = task >> 3;
            int j = m & (q - 1);
            int blk = m >> (6 - shift);
            int base2 = blk << (8 - shift);

            int ca = base2 + j;
            float4 a0 = lbuf4[lidx(ca, lpp)];
            float4 a1 = lbuf4[lidx(ca + q, lpp)];
            float4 a2 = lbuf4[lidx(ca + 2*q, lpp)];
            float4 a3 = lbuf4[lidx(ca + 3*q, lpp)];

            int e = j << shift;            // e < 64 for stages 0..2
            float w1r = __shfl(tw64r, e);
            float w1i = __shfl(tw64i, e);
            float w2r = fmaf(w1r, w1r, -(w1i * w1i));
            float w2i = 2.0f * w1r * w1i;
            float w3r = w2r * w1r - w2i * w1i;
            float w3i = w2r * w1i + w2i * w1r;

            float4 b0, b1, b2, b3;
            {
                float t0r = a0.x + a2.x, t0i = a0.y + a2.y;
                float t1r = a0.x - a2.x, t1i = a0.y - a2.y;
                float t2r = a1.x + a3.x, t2i = a1.y + a3.y;
                float t3r = a1.x - a3.x, t3i = a1.y - a3.y;
                b0.x = t0r + t2r;       b0.y = t0i + t2i;
                float b2r = t0r - t2r,  b2i = t0i - t2i;
                float b1r = t1r + t3i,  b1i = t1i - t3r;
                float b3r = t1r - t3i,  b3i = t1i + t3r;
                b1.x = b1r*w1r - b1i*w1i;  b1.y = b1r*w1i + b1i*w1r;
                b2.x = b2r*w2r - b2i*w2i;  b2.y = b2r*w2i + b2i*w2r;
                b3.x = b3r*w3r - b3i*w3i;  b3.y = b3r*w3i + b3i*w3r;
            }
            {
                float t0r = a0.z + a2.z, t0i = a0.w + a2.w;
                float t1r = a0.z - a2.z, t1i = a0.w - a2.w;
                float t2r = a1.z + a3.z, t2i = a1.w + a3.w;
                float t3r = a1.z - a3.z, t3i = a1.w - a3.w;
                b0.z = t0r + t2r;       b0.w = t0i + t2i;
                float b2r = t0r - t2r,  b2i = t0i - t2i;
                float b1r = t1r + t3i,  b1i = t1i - t3r;
                float b3r = t1r - t3i,  b3i = t1i + t3r;
                b1.z = b1r*w1r - b1i*w1i;  b1.w = b1r*w1i + b1i*w1r;
                b2.z = b2r*w2r - b2i*w2i;  b2.w = b2r*w2i + b2i*w2r;
                b3.z = b3r*w3r - b3i*w3i;  b3.w = b3r*w3i + b3i*w3r;
            }
            lbuf4[lidx(ca, lpp)]         = b0;
            lbuf4[lidx(ca + q, lpp)]     = b1;
            lbuf4[lidx(ca + 2*q, lpp)]   = b2;
            lbuf4[lidx(ca + 3*q, lpp)]   = b3;
        }
        __syncthreads();
    }

    // ---- FFT stage 3 (q=1, w=1) fused with digit-reverse + fftshift +
    //      NONTEMPORAL store: butterfly outputs ARE final rows ca..ca+3 ----
    #pragma unroll
    for (int it = 0; it < 2; ++it) {
        int task = it * 256 + t;
        int lpp = task & 7;
        int m = task >> 3;                 // 0..63
        int ca = m << 2;
        float4 a0 = lbuf4[lidx(ca + 0, lpp)];
        float4 a1 = lbuf4[lidx(ca + 1, lpp)];
        float4 a2 = lbuf4[lidx(ca + 2, lpp)];
        float4 a3 = lbuf4[lidx(ca + 3, lpp)];

        float4 b0, b1, b2, b3;
        {
            float t0r = a0.x + a2.x, t0i = a0.y + a2.y;
            float t1r = a0.x - a2.x, t1i = a0.y - a2.y;
            float t2r = a1.x + a3.x, t2i = a1.y + a3.y;
            float t3r = a1.x - a3.x, t3i = a1.y - a3.y;
            b0.x = t0r + t2r;  b0.y = t0i + t2i;
            b2.x = t0r - t2r;  b2.y = t0i - t2i;
            b1.x = t1r + t3i;  b1.y = t1i - t3r;
            b3.x = t1r - t3i;  b3.y = t1i + t3r;
        }
        {
            float t0r = a0.z + a2.z, t0i = a0.w + a2.w;
            float t1r = a0.z - a2.z, t1i = a0.w - a2.w;
            float t2r = a1.z + a3.z, t2i = a1.w + a3.w;
            float t3r = a1.z - a3.z, t3i = a1.w - a3.w;
            b0.z = t0r + t2r;  b0.w = t0i + t2i;
            b2.z = t0r - t2r;  b2.w = t0i - t2i;
            b1.z = t1r + t3i;  b1.w = t1i - t3r;
            b3.z = t1r - t3i;  b3.w = t1i + t3r;
        }

        float4 bb[4] = { b0, b1, b2, b3 };
        #pragma unroll
        for (int mm = 0; mm < 4; ++mm) {
            int cout = digitrev_shift(ca + mm);
            float4 v = bb[mm];
            if (interleaved) {
                size_t fi = 2 * ((size_t)(b * NC + cout) * NL + l0) + 4 * lpp;
                if (fi + 4 <= (size_t)out_size) {
                    vf4 o4; o4.x = v.x; o4.y = v.y; o4.z = v.z; o4.w = v.w;
                    __builtin_nontemporal_store(o4, (vf4*)(out + fi));
                }
            } else {
                size_t fi = (size_t)(b * NC + cout) * NL + l0 + 2 * lpp;
                if (fi + 2 <= (size_t)out_size) {
                    vf2 o2; o2.x = v.x; o2.y = v.z;
                    __builtin_nontemporal_store(o2, (vf2*)(out + fi));
                }
            }
        }
    }

    // ---- block stats -> dedicated slot (reduce via LDS alias) ----
    #pragma unroll
    for (int off = 32; off > 0; off >>= 1) {
        tsr += __shfl_down(tsr, off);
        tsi += __shfl_down(tsi, off);
        tsq += __shfl_down(tsq, off);
    }
    __syncthreads();                        // stage-3 LDS reads complete
    float* redf = (float*)lbuf4;
    if (lane == 0) { redf[wv*3+0] = tsr; redf[wv*3+1] = tsi; redf[wv*3+2] = tsq; }
    __syncthreads();
    if (t == 0) {
        float a0 = 0.0f, a1 = 0.0f, a2 = 0.0f;
        #pragma unroll
        for (int i = 0; i < 4; ++i) { a0 += redf[i*3]; a1 += redf[i*3+1]; a2 += redf[i*3+2]; }
        g_part[b * NSL + st] = make_float4(a0, a1, a2, 0.0f);
    }
}

// ---------------------------------------------------------------------------
// Per-batch inv_std from g_part (each block redundantly reduces its own
// batch's 256 slots -- 4 KB, L2-hot) + contiguous nontemporal scale of its
// out range. XCD-affine: block j -> batch j&7 (same swizzle as fused).
// ---------------------------------------------------------------------------
__global__ __launch_bounds__(256) void scale_out_kernel(
    float* __restrict__ out, int out_size)
{
    __shared__ float sred[13];
    const int t = threadIdx.x;
    const int j = blockIdx.x;               // 0..2047
    const int b = j & 7;                    // batch == XCD
    const int seg = j >> 3;                 // 256 segments per batch
    const int lane = t & 63, wv = t >> 6;

    // reduce batch b's 256 slots (thread t -> slot t)
    float4 p = g_part[b * NSL + t];
    float psr = p.x, psi = p.y, psq = p.z;
    #pragma unroll
    for (int off = 32; off > 0; off >>= 1) {
        psr += __shfl_down(psr, off);
        psi += __shfl_down(psi, off);
        psq += __shfl_down(psq, off);
    }
    if (lane == 0) { sred[wv*3+0] = psr; sred[wv*3+1] = psi; sred[wv*3+2] = psq; }
    __syncthreads();
    if (t == 0) {
        float a0 = 0.0f, a1 = 0.0f, a2 = 0.0f;
        #pragma unroll
        for (int i = 0; i < 4; ++i) { a0 += sred[i*3]; a1 += sred[i*3+1]; a2 += sred[i*3+2]; }
        const float n = (float)(NC * NL);
        float var = (a2 - (a0*a0 + a1*a1)/n) / (n - 1.0f);
        sred[12] = rsqrtf(var);
    }
    __syncthreads();
    const float inv = sred[12];

    const int fpbatch = out_size >> 3;      // floats per batch
    const int fpseg = fpbatch >> 8;         // floats per segment
    const int base = b * fpbatch + seg * fpseg;
    if ((fpseg & 3) == 0 && ((size_t)(out + base) & 15) == 0) {
        const int n4 = fpseg >> 2;
        for (int i = t; i < n4; i += 256) {
            vf4* p4 = (vf4*)(out + base) + i;
            vf4 v = __builtin_nontemporal_load(p4);
            v.x *= inv; v.y *= inv; v.z *= inv; v.w *= inv;
            __builtin_nontemporal_store(v, p4);
        }
    } else {
        for (int i = t; i < fpseg; i += 256) out[base + i] *= inv;
    }
    // tail (out_size not divisible by 2048): belongs to the last batch,
    // and block j==2047 has b==7.
    if (j == 2047) {
        for (int i = ((out_size >> 11) << 11) + t; i < out_size; i += 256)
            out[i] *= inv;
    }
}

extern "C" void kernel_launch(void* const* d_in, const int* in_sizes, int n_in,
                              void* d_out, int out_size, void* d_ws, size_t ws_size,
                              hipStream_t stream)
{
    const float* x   = (const float*)d_in[0];
    const float* kre = (const float*)d_in[1];
    const float* kim = (const float*)d_in[2];
    const float* wm  = (const float*)d_in[3];
    const float* wa  = (const float*)d_in[4];
    float* out = (float*)d_out;
    (void)d_ws; (void)ws_size;

    fused_conv_fft_kernel<<<NB * NSL, 256, 0, stream>>>(x, kre, kim, wm, wa,
                                                        out, out_size);
    scale_out_kernel<<<2048, 256, 0, stream>>>(out, out_size);
}